// Round 6
// baseline (36.471 us; speedup 1.0000x reference)
//
#include <hip/hip_runtime.h>

// Bidirectional minGRU scan, linear-domain. Dense-access variant.
// x: (16, 512, 4096) f32.  out: (16, 256, 4096) f32.
// Row r = b*256 + c.  c<128: forward scan on h=x[b,c,:], g=x[b,c+128,:].
// c>=128: backward scan on h=x[b,256+j,:], g=x[b,384+j,:], output at the same
// (reversed) time index == flip(scan(flip)).
//
// Each thread owns FOUR 4-element segments at memory offsets 1024*q + 4*tid,
// so every wave load/store instruction covers 1024 contiguous bytes (full
// 128B lines): no write-allocate fetch, no L1 pressure from strided reads,
// no big LDS staging. Scan hierarchy:
//   per-segment affine compose (4 steps)
//   -> wave shfl inclusive scan per q (4 independent scans, no barriers)
//   -> 32-float LDS stage + ONE barrier; scalar chain stitches waves & q's.
// Scan-rank order for bwd rows = descending memory index; handled by
// block-uniform register swaps (constant indices) + shfl_down instead of up.

#define T_LEN 4096
#define NTHR 256

__global__ __launch_bounds__(NTHR, 6) void mingru_bidir_kernel(
    const float* __restrict__ x, float* __restrict__ out) {
  const int row = blockIdx.x;          // [0, 16*256)
  const int b   = row >> 8;
  const int c   = row & 255;
  const int tid = threadIdx.x;
  const int lane = tid & 63;
  const int wid  = tid >> 6;
  const bool bwd = (c >= 128);
  const int j = c & 127;

  const float* __restrict__ hptr =
      x + ((size_t)b * 512 + (bwd ? 256 : 0) + j) * T_LEN;
  const float* __restrict__ gptr =
      x + ((size_t)b * 512 + (bwd ? 384 : 128) + j) * T_LEN;
  float* __restrict__ optr = out + ((size_t)b * 256 + c) * T_LEN;

  // cc/vv: [q][e], e in SCAN order within the segment.
  float cc[4][4], vv[4][4];

  #pragma unroll
  for (int q = 0; q < 4; ++q) {
    const int m0 = (q << 10) + (tid << 2);   // dense: 1KB/wave-instruction
    const float4 h4 = *reinterpret_cast<const float4*>(hptr + m0);
    const float4 g4 = *reinterpret_cast<const float4*>(gptr + m0);
    const float hs[4] = {h4.x, h4.y, h4.z, h4.w};
    const float gs[4] = {g4.x, g4.y, g4.z, g4.w};
    #pragma unroll
    for (int r = 0; r < 4; ++r) {
      const float h = hs[r];
      const float g = gs[r];
      // h' = copysign(max(|h|, EPS), h)  (h==0 -> +EPS, matches reference)
      const float ah = fmaxf(fabsf(h), 1e-6f);
      const float hp = (h < 0.0f) ? -ah : ah;
      // sigmoid(g) via stable form + fast rcp; sigmoid(-g) = 1 - sigmoid(g)
      const float eg  = __expf(-fabsf(g));
      const float inv = __builtin_amdgcn_rcpf(1.0f + eg);
      const float sg  = (g >= 0.0f) ? inv : eg * inv;
      const float co  = 1.0f - sg;
      const float va  = sg * hp;
      if (bwd) { cc[q][3 - r] = co; vv[q][3 - r] = va; }  // constant indices
      else     { cc[q][r]     = co; vv[q][r]     = va; }
    }
  }

  // Put q-arrays in scan-rank order: bwd rank = descending q (swap 0<->3,1<->2).
  if (bwd) {
    #pragma unroll
    for (int e = 0; e < 4; ++e) {
      float t;
      t = cc[0][e]; cc[0][e] = cc[3][e]; cc[3][e] = t;
      t = cc[1][e]; cc[1][e] = cc[2][e]; cc[2][e] = t;
      t = vv[0][e]; vv[0][e] = vv[3][e]; vv[3][e] = t;
      t = vv[1][e]; vv[1][e] = vv[2][e]; vv[2][e] = t;
    }
  }

  // Per-segment affine aggregates (C,V): state_out = C*state_in + V.
  float C[4], V[4];
  #pragma unroll
  for (int q = 0; q < 4; ++q) {
    C[q] = cc[q][0]; V[q] = vv[q][0];
    #pragma unroll
    for (int e = 1; e < 4; ++e) {
      V[q] = cc[q][e] * V[q] + vv[q][e];
      C[q] = C[q] * cc[q][e];
    }
  }

  // Wave-inclusive scan per q. Lane-rank: fwd ascending lane, bwd descending.
  if (!bwd) {
    #pragma unroll
    for (int q = 0; q < 4; ++q) {
      #pragma unroll
      for (int off = 1; off < 64; off <<= 1) {
        const float pc = __shfl_up(C[q], off);
        const float pv = __shfl_up(V[q], off);
        if (lane >= off) { V[q] = C[q] * pv + V[q]; C[q] = C[q] * pc; }
      }
    }
  } else {
    #pragma unroll
    for (int q = 0; q < 4; ++q) {
      #pragma unroll
      for (int off = 1; off < 64; off <<= 1) {
        const float pc = __shfl_down(C[q], off);
        const float pv = __shfl_down(V[q], off);
        if (lane < 64 - off) { V[q] = C[q] * pv + V[q]; C[q] = C[q] * pc; }
      }
    }
  }

  // Cross-wave / cross-q stitch: 32 floats through LDS, one barrier.
  __shared__ float sC[4][4], sV[4][4];   // [wid][q-rank]
  if (lane == (bwd ? 0 : 63)) {          // last lane in rank order holds wave agg
    #pragma unroll
    for (int q = 0; q < 4; ++q) { sC[wid][q] = C[q]; sV[wid][q] = V[q]; }
  }
  __syncthreads();

  // Scalar state chain in rank order (initial state 0); capture my wave's
  // incoming state per q. All threads compute the same broadcast chain.
  float myin[4];
  float s = 0.0f;
  if (!bwd) {
    #pragma unroll
    for (int q = 0; q < 4; ++q) {
      #pragma unroll
      for (int w = 0; w < 4; ++w) {
        if (w == wid) myin[q] = s;
        s = sC[w][q] * s + sV[w][q];
      }
    }
  } else {
    #pragma unroll
    for (int q = 0; q < 4; ++q) {
      #pragma unroll
      for (int w = 3; w >= 0; --w) {
        if (w == wid) myin[q] = s;
        s = sC[w][q] * s + sV[w][q];
      }
    }
  }

  // Per q: thread-incoming state = prev-lane inclusive aggregate applied to
  // the wave-incoming state; then replay the 4 steps and store densely.
  #pragma unroll
  for (int q = 0; q < 4; ++q) {
    const float pc = bwd ? __shfl_down(C[q], 1) : __shfl_up(C[q], 1);
    const float pv = bwd ? __shfl_down(V[q], 1) : __shfl_up(V[q], 1);
    const bool first = bwd ? (lane == 63) : (lane == 0);
    float st = first ? myin[q] : pc * myin[q] + pv;

    float o[4];
    #pragma unroll
    for (int e = 0; e < 4; ++e) {
      st = cc[q][e] * st + vv[q][e];
      o[e] = st;
    }
    const int qmem = bwd ? 3 - q : q;
    const float4 o4 = bwd ? make_float4(o[3], o[2], o[1], o[0])
                          : make_float4(o[0], o[1], o[2], o[3]);
    *reinterpret_cast<float4*>(optr + (qmem << 10) + (tid << 2)) = o4;
  }
}

extern "C" void kernel_launch(void* const* d_in, const int* in_sizes, int n_in,
                              void* d_out, int out_size, void* d_ws, size_t ws_size,
                              hipStream_t stream) {
  const float* x = (const float*)d_in[0];
  float* out = (float*)d_out;
  const int rows = 16 * 256;  // one block per output row
  mingru_bidir_kernel<<<rows, NTHR, 0, stream>>>(x, out);
}

// Round 7
// 35.003 us; speedup vs baseline: 1.0419x; 1.0419x over previous
//
#include <hip/hip_runtime.h>

// Bidirectional minGRU scan, linear-domain. Fully-dense chunk-4 variant.
// x: (16, 512, 4096) f32.  out: (16, 256, 4096) f32.
// Row r = b*256 + c.  c<128: forward scan on h=x[b,c,:], g=x[b,c+128,:].
// c>=128: backward scan on h=x[b,256+j,:], g=x[b,384+j,:], output at the same
// (reversed) time index == flip(scan(flip)).
//
// 1024 threads/block, one block per row. Thread tid owns out[4*tid .. 4*tid+4):
// every wave-level load/store instruction covers 1024 CONTIGUOUS bytes (full
// 128B lines) -> no write-allocate fetch, no LDS data staging, no strided reads.
// Scan: 4-step local affine compose -> ONE wave shfl inclusive scan (6 steps)
// -> 16-wave stitch (32 floats LDS, ONE barrier, 16-fma broadcast chain)
// -> replay 4 steps. Backward rows: block-uniform register reversals
// (constant indices) + shfl_down instead of shfl_up + reversed chain.

#define T_LEN 4096
#define NTHR 1024

__global__ __launch_bounds__(NTHR) void mingru_bidir_kernel(
    const float* __restrict__ x, float* __restrict__ out) {
  const int row = blockIdx.x;          // [0, 16*256)
  const int b   = row >> 8;
  const int c   = row & 255;
  const int tid = threadIdx.x;
  const int lane = tid & 63;
  const int wid  = tid >> 6;           // 0..15
  const bool bwd = (c >= 128);
  const int j = c & 127;

  const float* __restrict__ hptr =
      x + ((size_t)b * 512 + (bwd ? 256 : 0) + j) * T_LEN;
  const float* __restrict__ gptr =
      x + ((size_t)b * 512 + (bwd ? 384 : 128) + j) * T_LEN;
  float* __restrict__ optr = out + ((size_t)b * 256 + c) * T_LEN;

  const int m0 = tid << 2;             // dense: 1KB per wave instruction

  const float4 h4 = *reinterpret_cast<const float4*>(hptr + m0);
  const float4 g4 = *reinterpret_cast<const float4*>(gptr + m0);
  const float hs[4] = {h4.x, h4.y, h4.z, h4.w};
  const float gs[4] = {g4.x, g4.y, g4.z, g4.w};

  // cc/vv in SCAN order (bwd: scan order = descending t within the segment).
  float cc[4], vv[4];
  #pragma unroll
  for (int r = 0; r < 4; ++r) {
    const float h = hs[r];
    const float g = gs[r];
    // h' = copysign(max(|h|, EPS), h)  (h==0 -> +EPS, matches reference)
    const float ah = fmaxf(fabsf(h), 1e-6f);
    const float hp = (h < 0.0f) ? -ah : ah;
    // sigmoid(g) via stable form + fast rcp; sigmoid(-g) = 1 - sigmoid(g)
    const float eg  = __expf(-fabsf(g));
    const float inv = __builtin_amdgcn_rcpf(1.0f + eg);
    const float sg  = (g >= 0.0f) ? inv : eg * inv;
    const float co  = 1.0f - sg;
    const float va  = sg * hp;
    if (bwd) { cc[3 - r] = co; vv[3 - r] = va; }   // constant indices
    else     { cc[r]     = co; vv[r]     = va; }
  }

  // Local composition: after this thread's 4 steps, state = C*x_in + V.
  float C = cc[0], V = vv[0];
  #pragma unroll
  for (int e = 1; e < 4; ++e) {
    V = cc[e] * V + vv[e];
    C = C * cc[e];
  }

  // Wave-inclusive scan. Lane-rank: fwd ascending lane, bwd descending.
  if (!bwd) {
    #pragma unroll
    for (int off = 1; off < 64; off <<= 1) {
      const float pc = __shfl_up(C, off);
      const float pv = __shfl_up(V, off);
      if (lane >= off) { V = C * pv + V; C = C * pc; }
    }
  } else {
    #pragma unroll
    for (int off = 1; off < 64; off <<= 1) {
      const float pc = __shfl_down(C, off);
      const float pv = __shfl_down(V, off);
      if (lane < 64 - off) { V = C * pv + V; C = C * pc; }
    }
  }

  // Cross-wave stitch: 16 wave aggregates through LDS, one barrier.
  __shared__ float sC[16], sV[16];
  if (lane == (bwd ? 0 : 63)) { sC[wid] = C; sV[wid] = V; }
  __syncthreads();

  // Broadcast scalar chain in rank order (initial state 0); capture my wave's
  // incoming state. All threads compute the same chain (reads broadcast).
  float myin = 0.0f;
  float s = 0.0f;
  if (!bwd) {
    #pragma unroll
    for (int w = 0; w < 16; ++w) {
      if (w == wid) myin = s;
      s = sC[w] * s + sV[w];
    }
  } else {
    #pragma unroll
    for (int w = 15; w >= 0; --w) {
      if (w == wid) myin = s;
      s = sC[w] * s + sV[w];
    }
  }

  // Thread-incoming state = prev-lane (in rank order) inclusive aggregate
  // applied to the wave-incoming state.
  const float pc = bwd ? __shfl_down(C, 1) : __shfl_up(C, 1);
  const float pv = bwd ? __shfl_down(V, 1) : __shfl_up(V, 1);
  const bool first = bwd ? (lane == 63) : (lane == 0);
  float st = first ? myin : pc * myin + pv;

  // Replay the 4 steps; store densely (reverse back to memory order if bwd).
  float o[4];
  #pragma unroll
  for (int e = 0; e < 4; ++e) {
    st = cc[e] * st + vv[e];
    o[e] = st;
  }
  const float4 o4 = bwd ? make_float4(o[3], o[2], o[1], o[0])
                        : make_float4(o[0], o[1], o[2], o[3]);
  *reinterpret_cast<float4*>(optr + m0) = o4;
}

extern "C" void kernel_launch(void* const* d_in, const int* in_sizes, int n_in,
                              void* d_out, int out_size, void* d_ws, size_t ws_size,
                              hipStream_t stream) {
  const float* x = (const float*)d_in[0];
  float* out = (float*)d_out;
  const int rows = 16 * 256;  // one block per output row
  mingru_bidir_kernel<<<rows, NTHR, 0, stream>>>(x, out);
}

// Round 8
// 34.424 us; speedup vs baseline: 1.0595x; 1.0168x over previous
//
#include <hip/hip_runtime.h>

// Bidirectional minGRU scan, linear-domain. (Best variant — R5 structure.)
// x: (16, 512, 4096) f32.  out: (16, 256, 4096) f32.
// Row r = b*256 + c.  c<128: forward scan on h=x[b,c,:], g=x[b,c+128,:].
// c>=128: backward scan on h=x[b,256+j,:], g=x[b,384+j,:], j=c-128, with the
// output written at the same (reversed) time index == flip(scan(flip)).
//
// Per block (256 threads = 4 waves): each thread owns 16 contiguous scan steps.
// (c_t, v_t) = (sigmoid(-g), sigmoid(g)*h'); compose locally; wave shfl scan;
// one LDS stage for the 4 wave aggregates; replay chunk from incoming state.
//
// Stores go through LDS so each wave's global_store_dwordx4 covers 1024
// CONTIGUOUS bytes (full 128B lines) -> avoids L2 write-allocate line fetch
// that partial-line (16B/lane @ 64B stride) stores incur (~67MB hidden reads).
// LDS: 20-word stride per thread (pad 4) to reduce bank conflicts; 20480B
// exactly -> 8 blocks/CU. Wave aggregates live in pad holes.
//
// Tried and rejected (measured):
//  - nontemporal stores: WRITE_SIZE 64->97MB (partial-line HBM writes), 72us.
//  - dense strided-free loads via per-q wave scans (R6): 36.5us (scan overhead).
//  - chunk-4 / 1024-thread fully dense (R7): 35.0us.

#define T_LEN 4096
#define CHUNK 16
#define NTHR 256

__global__ __launch_bounds__(NTHR) void mingru_bidir_kernel(
    const float* __restrict__ x, float* __restrict__ out) {
  const int row = blockIdx.x;          // [0, 16*256)
  const int b   = row >> 8;
  const int c   = row & 255;
  const int tid = threadIdx.x;
  const int lane = tid & 63;
  const int wid  = tid >> 6;
  const bool bwd = (c >= 128);
  const int j = c & 127;

  const float* __restrict__ hptr =
      x + ((size_t)b * 512 + (bwd ? 256 : 0) + j) * T_LEN;
  const float* __restrict__ gptr =
      x + ((size_t)b * 512 + (bwd ? 384 : 128) + j) * T_LEN;
  float* __restrict__ optr = out + ((size_t)b * 256 + c) * T_LEN;

  // fwd: chunk covers t in [16*tid, 16*tid+15], scan order = increasing t.
  // bwd: scan steps s in [16*tid, 16*tid+15] map to t = 4095-s.
  const int t0 = bwd ? (T_LEN - CHUNK - (tid << 4)) : (tid << 4);

  float cc[CHUNK], vv[CHUNK];  // per-step (coeff, value), increasing-t order

  #pragma unroll
  for (int q = 0; q < 4; ++q) {
    const float4 h4 = *reinterpret_cast<const float4*>(hptr + t0 + 4 * q);
    const float4 g4 = *reinterpret_cast<const float4*>(gptr + t0 + 4 * q);
    const float hs[4] = {h4.x, h4.y, h4.z, h4.w};
    const float gs[4] = {g4.x, g4.y, g4.z, g4.w};
    #pragma unroll
    for (int r = 0; r < 4; ++r) {
      const int e = 4 * q + r;
      const float h = hs[r];
      const float g = gs[r];
      // h' = copysign(max(|h|, EPS), h)  (h==0 -> +EPS, matches reference)
      const float ah = fmaxf(fabsf(h), 1e-6f);
      const float hp = (h < 0.0f) ? -ah : ah;
      // sigmoid(g) via stable form + fast rcp; sigmoid(-g) = 1 - sigmoid(g)
      const float eg  = __expf(-fabsf(g));
      const float inv = __builtin_amdgcn_rcpf(1.0f + eg);
      const float sg  = (g >= 0.0f) ? inv : eg * inv;  // sigmoid(g)
      cc[e] = 1.0f - sg;
      vv[e] = sg * hp;
    }
  }

  // For backward rows, flip register arrays into scan order (uniform branch,
  // constant indices only -> stays in registers).
  if (bwd) {
    #pragma unroll
    for (int e = 0; e < CHUNK / 2; ++e) {
      float t1 = cc[e]; cc[e] = cc[CHUNK - 1 - e]; cc[CHUNK - 1 - e] = t1;
      float t2 = vv[e]; vv[e] = vv[CHUNK - 1 - e]; vv[CHUNK - 1 - e] = t2;
    }
  }

  // Local composition: after this thread's 16 steps, state = C*x_in + V.
  float C = cc[0], V = vv[0];
  #pragma unroll
  for (int e = 1; e < CHUNK; ++e) {
    V = cc[e] * V + vv[e];
    C = C * cc[e];
  }

  // Wave-inclusive scan of (C,V) over 64 lanes, no barriers.
  #pragma unroll
  for (int off = 1; off < 64; off <<= 1) {
    const float pc = __shfl_up(C, off);
    const float pv = __shfl_up(V, off);
    if (lane >= off) {
      V = C * pv + V;
      C = C * pc;
    }
  }

  // LDS: 256 threads x 20 words (16 data + 4 pad) = 20480 B exactly.
  // Wave-aggregate scalars live in pad holes: words 16..19 (sC), 36..39 (sV).
  __shared__ float lds[NTHR * 20];
  float* sC = lds + 16;
  float* sV = lds + 36;

  if (lane == 63) { sC[wid] = C; sV[wid] = V; }
  __syncthreads();
  float acc = 0.0f;  // state after all previous waves (initial state = 0)
  for (int w = 0; w < wid; ++w) acc = sC[w] * acc + sV[w];

  // Incoming state for this thread = inclusive(prev thread) applied to acc.
  const float pC = __shfl_up(C, 1);
  const float pV = __shfl_up(V, 1);
  const float incoming = (lane == 0) ? acc : pC * acc + pV;

  // Replay chunk from incoming state; vv becomes the outputs.
  float st = incoming;
  #pragma unroll
  for (int e = 0; e < CHUNK; ++e) {
    st = cc[e] * st + vv[e];
    vv[e] = st;
  }

  // Back to increasing-t order.
  if (bwd) {
    #pragma unroll
    for (int e = 0; e < CHUNK / 2; ++e) {
      float t2 = vv[e]; vv[e] = vv[CHUNK - 1 - e]; vv[CHUNK - 1 - e] = t2;
    }
  }

  // Logical chunk index within the row (bwd rows own chunk 255-tid).
  const int jj = bwd ? (NTHR - 1 - tid) : tid;

  __syncthreads();  // everyone done reading sC/sV before pads' neighbors fly
  #pragma unroll
  for (int q = 0; q < 4; ++q) {
    *reinterpret_cast<float4*>(&lds[20 * jj + 4 * q]) =
        make_float4(vv[4 * q], vv[4 * q + 1], vv[4 * q + 2], vv[4 * q + 3]);
  }
  __syncthreads();

  // Dense stores: instruction q, thread tid -> out[q*1024 + 4*tid + k].
  // Each wave covers 1024 contiguous bytes per instruction (full lines).
  #pragma unroll
  for (int q = 0; q < 4; ++q) {
    const float4 o4 = *reinterpret_cast<const float4*>(
        &lds[1280 * q + 20 * (tid >> 2) + 4 * (tid & 3)]);
    *reinterpret_cast<float4*>(optr + 1024 * q + 4 * tid) = o4;
  }
}

extern "C" void kernel_launch(void* const* d_in, const int* in_sizes, int n_in,
                              void* d_out, int out_size, void* d_ws, size_t ws_size,
                              hipStream_t stream) {
  const float* x = (const float*)d_in[0];
  float* out = (float*)d_out;
  const int rows = 16 * 256;  // one block per output row
  mingru_bidir_kernel<<<rows, NTHR, 0, stream>>>(x, out);
}